// Round 8
// baseline (892.850 us; speedup 1.0000x reference)
//
#include <hip/hip_runtime.h>
#include <hip/hip_bf16.h>
#include <math.h>

#define N_NODES 100000
#define N_EDGES 1000000
#define NEG_SLOPE 0.2f
#define NBUCK 98        // ceil(100000/1024) node buckets
#define BSHIFT 10       // 1024 nodes per bucket
#define SLAB 12288      // slab capacity per bucket (mean 10240, sigma ~101 -> 20 sigma headroom)
#define BINA_EDGES 4096
#define H0_BLOCKS 12500 // (N_NODES*32)/256
#define CONV_TOTAL (384 * 32 + 2 * 384 * 128)   // 110592
#define CONV_BLOCKS ((CONV_TOTAL + 255) / 256)  // 432

typedef short v8s __attribute__((ext_vector_type(8)));
typedef float v4f __attribute__((ext_vector_type(4)));

__device__ inline unsigned pack_bf16(float a, float b) {
    unsigned ua = __float_as_uint(a);
    unsigned ub = __float_as_uint(b);
    ua = (ua + 0x7FFFu + ((ua >> 16) & 1u)) >> 16;
    ub = (ub + 0x7FFFu + ((ub >> 16) & 1u)) >> 16;
    return ua | (ub << 16);
}
__device__ inline unsigned short bf16_rn(float x) {
    unsigned u = __float_as_uint(x);
    u = (u + 0x7FFFu + ((u >> 16) & 1u)) >> 16;
    return (unsigned short)u;
}
__device__ inline void unpack8(uint4 u, float* f) {
    f[0] = __uint_as_float(u.x << 16); f[1] = __uint_as_float(u.x & 0xFFFF0000u);
    f[2] = __uint_as_float(u.y << 16); f[3] = __uint_as_float(u.y & 0xFFFF0000u);
    f[4] = __uint_as_float(u.z << 16); f[5] = __uint_as_float(u.z & 0xFFFF0000u);
    f[6] = __uint_as_float(u.w << 16); f[7] = __uint_as_float(u.w & 0xFFFF0000u);
}

// ---------------- CSR build: two-level LDS-binned counting sort ----------------

__global__ __launch_bounds__(256) void binA_kernel(
    const int* __restrict__ src, const int* __restrict__ dst,
    int* __restrict__ gcursor, int* __restrict__ tmp) {
    __shared__ int bstart[NBUCK];
    __shared__ int addrbase[NBUCK];
    __shared__ int bcur[NBUCK];
    __shared__ int s[256];
    __shared__ int staged_val[BINA_EDGES];
    __shared__ int staged_addr[BINA_EDGES];
    const int tid = threadIdx.x;
    const int base = blockIdx.x * BINA_EDGES;
    const int ecount = min(BINA_EDGES, N_EDGES - base);

    if (tid < NBUCK) bcur[tid] = 0;
    __syncthreads();
    for (int j = tid; j < ecount; j += 256) {
        int d = dst[base + j];
        atomicAdd(&bcur[d >> BSHIFT], 1);
    }
    __syncthreads();
    int own = (tid < NBUCK) ? bcur[tid] : 0;
    s[tid] = own;
    __syncthreads();
    for (int off = 1; off < 256; off <<= 1) {
        int u = (tid >= off) ? s[tid - off] : 0;
        __syncthreads();
        s[tid] += u;
        __syncthreads();
    }
    if (tid < NBUCK) {
        int excl = s[tid] - own;
        bstart[tid] = excl;
        int resv = atomicAdd(&gcursor[tid], own);
        addrbase[tid] = resv - excl;
    }
    __syncthreads();
    if (tid < NBUCK) bcur[tid] = bstart[tid];
    __syncthreads();
    for (int j = tid; j < ecount; j += 256) {
        int d = dst[base + j];
        int sr = src[base + j];
        int bk = d >> BSHIFT;
        int lpos = atomicAdd(&bcur[bk], 1);
        staged_val[lpos] = ((d & ((1 << BSHIFT) - 1)) << 17) | sr;
        staged_addr[lpos] = addrbase[bk] + lpos;
    }
    __syncthreads();
    for (int j = tid; j < ecount; j += 256)
        tmp[staged_addr[j]] = staged_val[j];
}

// Pass B: one block per bucket; per-block redundant scan of gcursor replaces a
// separate bucket_scan launch.
__global__ __launch_bounds__(256) void binB_kernel(
    const int* __restrict__ tmp, const int* __restrict__ gcursor,
    int* __restrict__ row_ptr, int* __restrict__ srcs) {
    __shared__ int hist[1024];
    __shared__ int tsum[256];
    __shared__ int sscan[128];
    const int b = blockIdx.x;
    const int tid = threadIdx.x;
    const int base = b * SLAB;
    const int cnt = gcursor[b] - base;
    const int node0 = b << BSHIFT;
    const int nodes_in = min(1024, N_NODES - node0);

    if (b == 0 && tid == 0) row_ptr[N_NODES] = N_EDGES;

    if (tid < 128) {
        int vv = (tid < NBUCK) ? (gcursor[tid] - tid * SLAB) : 0;
        sscan[tid] = vv;
    }
    __syncthreads();
    for (int off = 1; off < 128; off <<= 1) {
        int u = 0;
        if (tid < 128 && tid >= off) u = sscan[tid - off];
        __syncthreads();
        if (tid < 128) sscan[tid] += u;
        __syncthreads();
    }
    const int gb = sscan[b] - cnt;

    for (int i = tid; i < 1024; i += 256) hist[i] = 0;
    __syncthreads();
    for (int i = tid; i < cnt; i += 256)
        atomicAdd(&hist[tmp[base + i] >> 17], 1);
    __syncthreads();
    int v[4], local = 0;
#pragma unroll
    for (int j = 0; j < 4; ++j) {
        v[j] = hist[tid * 4 + j];
        local += v[j];
    }
    tsum[tid] = local;
    __syncthreads();
    for (int off = 1; off < 256; off <<= 1) {
        int u = (tid >= off) ? tsum[tid - off] : 0;
        __syncthreads();
        tsum[tid] += u;
        __syncthreads();
    }
    int run = tsum[tid] - local;
#pragma unroll
    for (int j = 0; j < 4; ++j) {
        hist[tid * 4 + j] = run;
        run += v[j];
    }
    __syncthreads();
    for (int i = tid; i < nodes_in; i += 256)
        row_ptr[node0 + i] = gb + hist[i];
    __syncthreads();
    for (int i = tid; i < cnt; i += 256) {
        int e = tmp[base + i];
        int pos = atomicAdd(&hist[e >> 17], 1);
        srcs[gb + pos] = e & 0x1FFFF;
    }
}

// ---------------- prep: h0 + weight convert + gcursor init in ONE launch -----
__device__ inline void conv_one(int idx, int K, const float* __restrict__ Wl,
                                const float* __restrict__ Wr, const float* __restrict__ Ws,
                                unsigned short* __restrict__ wt) {
    int n = idx / K;
    int k = idx - n * K;
    int sec = n >> 7;
    int nn = n & 127;
    const float* W = (sec == 0) ? Wl : (sec == 1) ? Wr : Ws;
    wt[idx] = bf16_rn(W[k * 128 + nn]);
}

__global__ void prep_kernel(
    const float* __restrict__ x, const float* __restrict__ W0, unsigned short* __restrict__ h,
    const float* __restrict__ fWl, const float* __restrict__ fWr, const float* __restrict__ fWs,
    const float* __restrict__ mWl, const float* __restrict__ mWr, const float* __restrict__ mWs,
    const float* __restrict__ lWl, const float* __restrict__ lWr, const float* __restrict__ lWs,
    unsigned short* __restrict__ wt_f, unsigned short* __restrict__ wt_m,
    unsigned short* __restrict__ wt_l, int* __restrict__ gcursor) {
    const int bid = blockIdx.x;
    if (bid < H0_BLOCKS) {
        int tid = bid * 256 + threadIdx.x;
        int col = tid & 31;
        int row = tid >> 5;
        const float* xr = x + row * 64;
        float acc = 0.f;
#pragma unroll
        for (int k = 0; k < 64; ++k) acc = fmaf(xr[k], W0[k * 32 + col], acc);
        h[row * 32 + col] = bf16_rn(fmaxf(acc, 0.f));
    } else {
        int t = (bid - H0_BLOCKS) * 256 + threadIdx.x;
        if (t < NBUCK) gcursor[t] = t * SLAB;
        if (t < 384 * 32) {
            conv_one(t, 32, fWl, fWr, fWs, wt_f);
        } else if (t < 384 * 32 + 384 * 128) {
            conv_one(t - 384 * 32, 128, mWl, mWr, mWs, wt_m);
        } else if (t < CONV_TOTAL) {
            conv_one(t - 384 * 32 - 384 * 128, 128, lWl, lWr, lWs, wt_l);
        }
    }
}

// ---------------- MFMA mm3: [N,K]bf16 @ Wt^T -> xl|xr|skip (layer f only) ----
// r5-proven shape: 64 rows per 1-wave block, LDS-staged dense stores.
template <int K>
__global__ __launch_bounds__(64) void mm3_mfma(
    const unsigned short* __restrict__ A, const unsigned short* __restrict__ Wt,
    const float* __restrict__ bl, const float* __restrict__ br, const float* __restrict__ bs,
    const float* __restrict__ cb,
    unsigned short* __restrict__ xl_bf, unsigned short* __restrict__ xr_bf,
    unsigned short* __restrict__ sk_bf) {
    __shared__ uint4 tile4[64 * 10];  // 64 rows x 160 B
    const int lane = threadIdx.x & 63;
    const int q = lane >> 4;
    const int li = lane & 15;
    const int r0 = blockIdx.x * 64;
    constexpr int KS = K / 32;

    v8s a[4][KS];
#pragma unroll
    for (int mi = 0; mi < 4; ++mi) {
        int row = r0 + mi * 16 + li;
        row = row < N_NODES ? row : N_NODES - 1;
#pragma unroll
        for (int ks = 0; ks < KS; ++ks)
            a[mi][ks] = *(const v8s*)&A[(size_t)row * K + ks * 32 + q * 8];
    }

    const int frow = lane >> 3;
    const int fchunk = lane & 7;

    for (int t = 0; t < 6; ++t) {
        const int sec = t >> 1;
        const int c0 = (t & 1) * 64;
        v4f acc[4][4];
#pragma unroll
        for (int mi = 0; mi < 4; ++mi)
#pragma unroll
            for (int ni = 0; ni < 4; ++ni) acc[mi][ni] = (v4f)(0.f);

#pragma unroll
        for (int ks = 0; ks < KS; ++ks) {
            v8s b[4];
#pragma unroll
            for (int ni = 0; ni < 4; ++ni) {
                int col = sec * 128 + c0 + ni * 16 + li;
                b[ni] = *(const v8s*)&Wt[(size_t)col * K + ks * 32 + q * 8];
            }
#pragma unroll
            for (int mi = 0; mi < 4; ++mi)
#pragma unroll
                for (int ni = 0; ni < 4; ++ni)
                    acc[mi][ni] = __builtin_amdgcn_mfma_f32_16x16x32_bf16(b[ni], a[mi][ks], acc[mi][ni], 0, 0, 0);
        }

        unsigned short* dstp = (sec == 0) ? xl_bf : (sec == 1) ? xr_bf : sk_bf;
#pragma unroll
        for (int ni = 0; ni < 4; ++ni) {
            int cbase = c0 + ni * 16 + q * 4;
            float4 b4;
            if (sec == 0) b4 = *(const float4*)&bl[cbase];
            else if (sec == 1) b4 = *(const float4*)&br[cbase];
            else {
                float4 t1 = *(const float4*)&bs[cbase];
                float4 t2 = *(const float4*)&cb[cbase];
                b4 = make_float4(t1.x + t2.x, t1.y + t2.y, t1.z + t2.z, t1.w + t2.w);
            }
#pragma unroll
            for (int mi = 0; mi < 4; ++mi) {
                v4f v = acc[mi][ni];
                uint2 pk;
                pk.x = pack_bf16(v[0] + b4.x, v[1] + b4.y);
                pk.y = pack_bf16(v[2] + b4.z, v[3] + b4.w);
                int lrow = mi * 16 + li;
                *(uint2*)((char*)tile4 + lrow * 160 + ni * 32 + q * 8) = pk;
            }
        }
#pragma unroll
        for (int j = 0; j < 8; ++j) {
            int lrow = j * 8 + frow;
            int grow = r0 + lrow;
            if (grow < N_NODES) {
                uint4 v = *(const uint4*)((const char*)tile4 + lrow * 160 + fchunk * 16);
                *(uint4*)((char*)dstp + (size_t)grow * 256 + c0 * 2 + fchunk * 16) = v;
            }
        }
    }
}

// ---------------- shared agg macros ----------------
#define GATHER4(S) (*(const uint4*)((const char*)xlb4 + (((unsigned)(S)) << 8) + ((unsigned)li << 4)))

#define AGG_BODY(XC, SVC, CB)                                               \
    {                                                                       \
        float xf[8];                                                        \
        unpack8(XC, xf);                                                    \
        bool vld = (CB) + g < end;                                          \
        if ((CB) + 12 < end) XC = GATHER4(SVC);                             \
        if ((CB) + 24 < end) {                                              \
            int ii = (CB) + 24 + g;                                         \
            SVC = srcs[ii < end ? ii : em1];                                \
        }                                                                   \
        float p1 = 0.f, p2 = 0.f;                                           \
        _Pragma("unroll") for (int i = 0; i < 8; ++i) {                     \
            float e_ = xf[i] + xr_f[i];                                     \
            p1 = fmaf(e_, at_f[i], p1);                                     \
            p2 = fmaf(fabsf(e_), at_f[i], p2);                              \
        }                                                                   \
        float p = fmaf(0.6f, p1, 0.4f * p2);                                \
        p += __shfl_xor(p, 1);                                              \
        p += __shfl_xor(p, 2);                                              \
        float w = vld ? __expf(p) : 0.f;                                    \
        lsum += w;                                                          \
        _Pragma("unroll") for (int i = 0; i < 8; ++i)                       \
            acc[i] = fmaf(xf[i], w, acc[i]);                                \
    }

#define PREFETCH_ROW(B, E)                                                  \
    if ((B) < (E)) {                                                        \
        const int em1_ = (E) - 1;                                           \
        int ii;                                                             \
        ii = (B) + g;      sv0 = srcs[ii < (E) ? ii : em1_];                \
        ii = (B) + 4 + g;  sv1 = srcs[ii < (E) ? ii : em1_];                \
        ii = (B) + 8 + g;  sv2 = srcs[ii < (E) ? ii : em1_];                \
        x0 = GATHER4(sv0);                                                  \
        x1 = GATHER4(sv1);                                                  \
        x2 = GATHER4(sv2);                                                  \
        ii = (B) + 12 + g; sv0 = srcs[ii < (E) ? ii : em1_];                \
        ii = (B) + 16 + g; sv1 = srcs[ii < (E) ? ii : em1_];                \
        ii = (B) + 20 + g; sv2 = srcs[ii < (E) ? ii : em1_];                \
    }

// ---------------- FUSED agg(layer i) + mm3(layer i+1): h never hits memory ---
// 1563 blocks x 4 waves; block owns nodes [r0, r0+64).
// Phase A: wave w aggs nodes [r0+16w, r0+16w+16) with a cross-node software
//   pipeline (next node's row_ptr/xr/sk/srcs/gathers issued under the current
//   node's body+epilogue -- r2-proven mechanics, block-contiguous nodes keep
//   the r1/r5 locality). Result h-rows go to an LDS tile, 272-B row stride
//   (write: row-local dense = conflict-free; read: 16 rows x b128 ~2-way).
// Phase B: barrier -> each wave loads all 64 rows' a-frags from LDS (r5's
//   16-chain ILP preserved) -> barrier -> sections {w,(w+4)<=5} per wave, each
//   staged in a per-wave LDS tile and flushed as dense 128-B row stores.
// Saves 51.2 MB of h write+read per layer boundary (~16 us at 3.2 TB/s) + a
// launch gap. xl ping-pongs across kernels (random gather is cross-block);
// xr/sk are updated IN PLACE: phase A reads them only for the block's own
// rows, phase B rewrites exactly those rows after the barrier.
__global__ __launch_bounds__(256, 3) void aggmm_kernel(
    const uint4* __restrict__ xlb4, const uint4* __restrict__ xrb4,
    const uint4* __restrict__ skb4, const int* __restrict__ row_ptr,
    const int* __restrict__ srcs, const float* __restrict__ att,
    const unsigned short* __restrict__ Wt,
    const float* __restrict__ bl, const float* __restrict__ br,
    const float* __restrict__ bs, const float* __restrict__ cb,
    unsigned short* __restrict__ xl_out, unsigned short* __restrict__ xr_out,
    unsigned short* __restrict__ sk_out) {
    __shared__ uint4 smem4[2560];                 // 40960 B, reused across phases
    unsigned short* hT = (unsigned short*)smem4;  // phase A: 64 x 272 B = 17408 B
    char* stg = (char*)smem4;                     // phase B: 4 x 64 x 160 B = 40960 B

    const int lane = threadIdx.x & 63;
    const int g = lane >> 4, li = lane & 15;
    const int wave = threadIdx.x >> 6;
    const int r0 = blockIdx.x * 64;

    float at_f[8];
    *(float4*)&at_f[0] = *(const float4*)&att[li * 8];
    *(float4*)&at_f[4] = *(const float4*)&att[li * 8 + 4];

    // ---------- Phase A: aggregate 16 nodes per wave into LDS ----------
    int node = r0 + wave * 16;
    const int nodeEnd = min(node + 16, N_NODES);
    if (node < nodeEnd) {
        int rb = row_ptr[node];
        int re = row_ptr[node + 1];
        uint4 xru = xrb4[(size_t)node * 16 + li];
        uint4 sku = skb4[(size_t)node * 16 + li];
        int beg = __builtin_amdgcn_readfirstlane(rb);
        int end = __builtin_amdgcn_readfirstlane(re);
        int sv0 = 0, sv1 = 0, sv2 = 0;
        uint4 x0 = {}, x1 = {}, x2 = {};
        PREFETCH_ROW(beg, end);

        for (;;) {
            const int next = node + 1;
            if (next < nodeEnd) {
                rb = row_ptr[next];
                re = row_ptr[next + 1];
            }
            float xr_f[8];
            unpack8(xru, xr_f);
            if (next < nodeEnd) xru = xrb4[(size_t)next * 16 + li];

            float acc[8];
#pragma unroll
            for (int i = 0; i < 8; ++i) acc[i] = 0.f;
            float lsum = 0.f;

            if (beg < end) {
                const int em1 = end - 1;
                for (int cb_ = beg; cb_ < end; cb_ += 12) {
                    AGG_BODY(x0, sv0, cb_)
                    if (cb_ + 4 < end) AGG_BODY(x1, sv1, cb_ + 4)
                    if (cb_ + 8 < end) AGG_BODY(x2, sv2, cb_ + 8)
                }
            }

            int nbeg = 0, nend = 0;
            if (next < nodeEnd) {
                nbeg = __builtin_amdgcn_readfirstlane(rb);
                nend = __builtin_amdgcn_readfirstlane(re);
                PREFETCH_ROW(nbeg, nend);
            }

#pragma unroll
            for (int i = 0; i < 8; ++i) {
                acc[i] += __shfl_xor(acc[i], 16);
                acc[i] += __shfl_xor(acc[i], 32);
            }
            lsum += __shfl_xor(lsum, 16);
            lsum += __shfl_xor(lsum, 32);

            float inv = (lsum > 0.f) ? 1.f / lsum : 0.f;
            float sk_f[8];
            unpack8(sku, sk_f);
            if (next < nodeEnd) sku = skb4[(size_t)next * 16 + li];
            float o[8];
#pragma unroll
            for (int i = 0; i < 8; ++i) o[i] = fmaxf(fmaf(acc[i], inv, sk_f[i]), 0.f);  // relu

            // full-wave dense LDS store (row-local 256 B -> conflict-free)
            float oa = (g == 0) ? o[0] : (g == 1) ? o[2] : (g == 2) ? o[4] : o[6];
            float ob = (g == 0) ? o[1] : (g == 1) ? o[3] : (g == 2) ? o[5] : o[7];
            *(unsigned*)((char*)hT + (node - r0) * 272 + li * 16 + g * 4) = pack_bf16(oa, ob);

            if (next >= nodeEnd) break;
            node = next;
            beg = nbeg;
            end = nend;
        }
    }
    __syncthreads();

    // ---------- Phase B: mm3 of next layer from the LDS h-tile ----------
    const int q = lane >> 4;
    v8s a[4][4];
#pragma unroll
    for (int mi = 0; mi < 4; ++mi)
#pragma unroll
        for (int ks = 0; ks < 4; ++ks)
            a[mi][ks] = *(const v8s*)((const char*)hT + (mi * 16 + li) * 272 + ks * 64 + q * 16);
    __syncthreads();  // hT fully consumed; stg may now overwrite it

    const int frow = lane >> 3;
    const int fchunk = lane & 7;
    char* mystg = stg + wave * 10240;

#pragma unroll 1
    for (int si = 0; si < 2; ++si) {
        const int s = (si == 0) ? wave : wave + 4;   // w0:{0,4} w1:{1,5} w2:{2} w3:{3}
        if (s > 5) break;
        const int sec = s >> 1;
        const int c0 = (s & 1) * 64;
        v4f acc[4][4];
#pragma unroll
        for (int mi = 0; mi < 4; ++mi)
#pragma unroll
            for (int ni = 0; ni < 4; ++ni) acc[mi][ni] = (v4f)(0.f);

#pragma unroll
        for (int ks = 0; ks < 4; ++ks) {
            v8s b[4];
#pragma unroll
            for (int ni = 0; ni < 4; ++ni) {
                int col = sec * 128 + c0 + ni * 16 + li;
                b[ni] = *(const v8s*)&Wt[(size_t)col * 128 + ks * 32 + q * 8];
            }
#pragma unroll
            for (int mi = 0; mi < 4; ++mi)
#pragma unroll
                for (int ni = 0; ni < 4; ++ni)
                    acc[mi][ni] = __builtin_amdgcn_mfma_f32_16x16x32_bf16(b[ni], a[mi][ks], acc[mi][ni], 0, 0, 0);
        }

        unsigned short* dstp = (sec == 0) ? xl_out : (sec == 1) ? xr_out : sk_out;
#pragma unroll
        for (int ni = 0; ni < 4; ++ni) {
            int cbase = c0 + ni * 16 + q * 4;
            float4 b4;
            if (sec == 0) b4 = *(const float4*)&bl[cbase];
            else if (sec == 1) b4 = *(const float4*)&br[cbase];
            else {
                float4 t1 = *(const float4*)&bs[cbase];
                float4 t2 = *(const float4*)&cb[cbase];
                b4 = make_float4(t1.x + t2.x, t1.y + t2.y, t1.z + t2.z, t1.w + t2.w);
            }
#pragma unroll
            for (int mi = 0; mi < 4; ++mi) {
                v4f v = acc[mi][ni];
                uint2 pk;
                pk.x = pack_bf16(v[0] + b4.x, v[1] + b4.y);
                pk.y = pack_bf16(v[2] + b4.z, v[3] + b4.w);
                int lrow = mi * 16 + li;
                *(uint2*)(mystg + lrow * 160 + ni * 32 + q * 8) = pk;
            }
        }
#pragma unroll
        for (int j = 0; j < 8; ++j) {
            int lrow = j * 8 + frow;
            int grow = r0 + lrow;
            if (grow < N_NODES) {
                uint4 v = *(const uint4*)(mystg + lrow * 160 + fchunk * 16);
                *(uint4*)((char*)dstp + (size_t)grow * 256 + c0 * 2 + fchunk * 16) = v;
            }
        }
    }
}

// ---------------- final GATv2 aggregation (layer l, fp32 out + L2 norm) -----
__global__ __launch_bounds__(256, 7) void agg_kernel(
    const uint4* __restrict__ xlb4, const uint4* __restrict__ xrb4,
    const uint4* __restrict__ skb4, const int* __restrict__ row_ptr,
    const int* __restrict__ srcs, const float* __restrict__ att,
    float* __restrict__ out_f) {
    int n = (blockIdx.x * blockDim.x + threadIdx.x) >> 6;
    if (n >= N_NODES) return;
    int lane = threadIdx.x & 63;
    int g = lane >> 4, li = lane & 15;

    const int beg = __builtin_amdgcn_readfirstlane(row_ptr[n]);
    const int end = __builtin_amdgcn_readfirstlane(row_ptr[n + 1]);

    uint4 xru = xrb4[(size_t)n * 16 + li];
    uint4 sku = skb4[(size_t)n * 16 + li];

    float at_f[8];
    *(float4*)&at_f[0] = *(const float4*)&att[li * 8];
    *(float4*)&at_f[4] = *(const float4*)&att[li * 8 + 4];
    float xr_f[8];
    unpack8(xru, xr_f);

    float acc[8];
#pragma unroll
    for (int i = 0; i < 8; ++i) acc[i] = 0.f;
    float lsum = 0.f;

    if (beg < end) {
        const int em1 = end - 1;
        int sv0 = 0, sv1 = 0, sv2 = 0;
        uint4 x0 = {}, x1 = {}, x2 = {};
        PREFETCH_ROW(beg, end);
        for (int cb = beg; cb < end; cb += 12) {
            AGG_BODY(x0, sv0, cb)
            if (cb + 4 < end) AGG_BODY(x1, sv1, cb + 4)
            if (cb + 8 < end) AGG_BODY(x2, sv2, cb + 8)
        }
    }

#pragma unroll
    for (int i = 0; i < 8; ++i) {
        acc[i] += __shfl_xor(acc[i], 16);
        acc[i] += __shfl_xor(acc[i], 32);
    }
    lsum += __shfl_xor(lsum, 16);
    lsum += __shfl_xor(lsum, 32);

    float inv = (lsum > 0.f) ? 1.f / lsum : 0.f;
    float sk_f[8];
    unpack8(sku, sk_f);
    float o[8];
#pragma unroll
    for (int i = 0; i < 8; ++i) o[i] = fmaf(acc[i], inv, sk_f[i]);
    float ss = 0.f;
#pragma unroll
    for (int i = 0; i < 8; ++i) ss = fmaf(o[i], o[i], ss);
    ss += __shfl_xor(ss, 1);
    ss += __shfl_xor(ss, 2);
    ss += __shfl_xor(ss, 4);
    ss += __shfl_xor(ss, 8);
    float r = 1.0f / sqrtf(ss);
#pragma unroll
    for (int i = 0; i < 8; ++i) o[i] *= r;

    float oa = (g == 0) ? o[0] : (g == 1) ? o[2] : (g == 2) ? o[4] : o[6];
    float ob = (g == 0) ? o[1] : (g == 1) ? o[3] : (g == 2) ? o[5] : o[7];
    float2 v2 = make_float2(oa, ob);
    *(float2*)((char*)out_f + (size_t)n * 512 + li * 32 + g * 8) = v2;
}

// ---------------- launch ----------------
extern "C" void kernel_launch(void* const* d_in, const int* in_sizes, int n_in,
                              void* d_out, int out_size, void* d_ws, size_t ws_size,
                              hipStream_t stream) {
    const float* x = (const float*)d_in[0];
    const int* ei = (const int*)d_in[1];
    const int* src = ei;
    const int* dst = ei + N_EDGES;
    const float* W0 = (const float*)d_in[2];

    const float* f_p[8];
    const float* m_p[8];
    const float* l_p[8];
    for (int i = 0; i < 8; ++i) f_p[i] = (const float*)d_in[3 + i];
    for (int i = 0; i < 8; ++i) m_p[i] = (const float*)d_in[11 + i];
    for (int i = 0; i < 8; ++i) l_p[i] = (const float*)d_in[19 + i];
    // indices: 0=Wl 1=bl 2=Wr 3=br 4=att 5=cb 6=Ws 7=bs

    char* ws = (char*)d_ws;
    unsigned short* xl_a = (unsigned short*)ws; ws += (size_t)N_NODES * 128 * 2;  // 25.6 MB
    unsigned short* xl_b = (unsigned short*)ws; ws += (size_t)N_NODES * 128 * 2;
    unsigned short* xr_s = (unsigned short*)ws; ws += (size_t)N_NODES * 128 * 2;
    unsigned short* sk_s = (unsigned short*)ws; ws += (size_t)N_NODES * 128 * 2;
    unsigned short* h0 = (unsigned short*)ws;   ws += (size_t)N_NODES * 32 * 2;   // 6.4 MB
    int* row_ptr = (int*)ws;       ws += (size_t)(N_NODES + 1) * 4;
    int* srcs = (int*)ws;          ws += (size_t)N_EDGES * 4;
    int* tmp = (int*)ws;           ws += (size_t)NBUCK * SLAB * 4;   // 4.8 MB slabs
    int* gcursor = (int*)ws;       ws += (size_t)NBUCK * 4;
    unsigned short* wt_f = (unsigned short*)ws; ws += (size_t)384 * 32 * 2;
    unsigned short* wt_m = (unsigned short*)ws; ws += (size_t)384 * 128 * 2;
    unsigned short* wt_l = (unsigned short*)ws; ws += (size_t)384 * 128 * 2;

    prep_kernel<<<H0_BLOCKS + CONV_BLOCKS, 256, 0, stream>>>(
        x, W0, h0,
        f_p[0], f_p[2], f_p[6], m_p[0], m_p[2], m_p[6], l_p[0], l_p[2], l_p[6],
        wt_f, wt_m, wt_l, gcursor);
    binA_kernel<<<(N_EDGES + BINA_EDGES - 1) / BINA_EDGES, 256, 0, stream>>>(src, dst, gcursor, tmp);
    binB_kernel<<<NBUCK, 256, 0, stream>>>(tmp, gcursor, row_ptr, srcs);

    const int gmm = (N_NODES + 63) / 64;
    const int gagg = (N_NODES * 64) / 256;
    float* out = (float*)d_out;

    // layer f projection (din=32) from h0
    mm3_mfma<32><<<gmm, 64, 0, stream>>>(h0, wt_f, f_p[1], f_p[3], f_p[7], f_p[5],
                                         xl_a, xr_s, sk_s);

    // fused: agg(f)+mm3(m1), agg(m1)+mm3(m2), agg(m2)+mm3(m3), agg(m3)+mm3(l)
    aggmm_kernel<<<gmm, 256, 0, stream>>>((uint4*)xl_a, (uint4*)xr_s, (uint4*)sk_s,
                                          row_ptr, srcs, f_p[4],
                                          wt_m, m_p[1], m_p[3], m_p[7], m_p[5],
                                          xl_b, xr_s, sk_s);
    aggmm_kernel<<<gmm, 256, 0, stream>>>((uint4*)xl_b, (uint4*)xr_s, (uint4*)sk_s,
                                          row_ptr, srcs, m_p[4],
                                          wt_m, m_p[1], m_p[3], m_p[7], m_p[5],
                                          xl_a, xr_s, sk_s);
    aggmm_kernel<<<gmm, 256, 0, stream>>>((uint4*)xl_a, (uint4*)xr_s, (uint4*)sk_s,
                                          row_ptr, srcs, m_p[4],
                                          wt_m, m_p[1], m_p[3], m_p[7], m_p[5],
                                          xl_b, xr_s, sk_s);
    aggmm_kernel<<<gmm, 256, 0, stream>>>((uint4*)xl_b, (uint4*)xr_s, (uint4*)sk_s,
                                          row_ptr, srcs, m_p[4],
                                          wt_l, l_p[1], l_p[3], l_p[7], l_p[5],
                                          xl_a, xr_s, sk_s);

    // final layer l aggregation: fp32 out + L2 normalize
    agg_kernel<<<gagg, 256, 0, stream>>>((uint4*)xl_a, (uint4*)xr_s, (uint4*)sk_s,
                                         row_ptr, srcs, l_p[4], out);
}

// Round 9
// 588.260 us; speedup vs baseline: 1.5178x; 1.5178x over previous
//
#include <hip/hip_runtime.h>
#include <hip/hip_bf16.h>
#include <math.h>

#define N_NODES 100000
#define N_EDGES 1000000
#define NEG_SLOPE 0.2f
#define NBUCK 98        // ceil(100000/1024) node buckets
#define BSHIFT 10       // 1024 nodes per bucket
#define SLAB 12288      // slab capacity per bucket (mean 10240, sigma ~101 -> 20 sigma headroom)
#define BINA_EDGES 4096
#define CONV_TOTAL (384 * 32 + 2 * 384 * 128)   // 110592
#define CONV_BLOCKS ((CONV_TOTAL + 255) / 256)  // 432

typedef short v8s __attribute__((ext_vector_type(8)));
typedef float v4f __attribute__((ext_vector_type(4)));

__device__ inline unsigned pack_bf16(float a, float b) {
    unsigned ua = __float_as_uint(a);
    unsigned ub = __float_as_uint(b);
    ua = (ua + 0x7FFFu + ((ua >> 16) & 1u)) >> 16;
    ub = (ub + 0x7FFFu + ((ub >> 16) & 1u)) >> 16;
    return ua | (ub << 16);
}
__device__ inline unsigned short bf16_rn(float x) {
    unsigned u = __float_as_uint(x);
    u = (u + 0x7FFFu + ((u >> 16) & 1u)) >> 16;
    return (unsigned short)u;
}
__device__ inline void unpack8(uint4 u, float* f) {
    f[0] = __uint_as_float(u.x << 16); f[1] = __uint_as_float(u.x & 0xFFFF0000u);
    f[2] = __uint_as_float(u.y << 16); f[3] = __uint_as_float(u.y & 0xFFFF0000u);
    f[4] = __uint_as_float(u.z << 16); f[5] = __uint_as_float(u.z & 0xFFFF0000u);
    f[6] = __uint_as_float(u.w << 16); f[7] = __uint_as_float(u.w & 0xFFFF0000u);
}

// ---------------- CSR build: two-level LDS-binned counting sort ----------------

__global__ __launch_bounds__(256) void binA_kernel(
    const int* __restrict__ src, const int* __restrict__ dst,
    int* __restrict__ gcursor, int* __restrict__ tmp) {
    __shared__ int bstart[NBUCK];
    __shared__ int addrbase[NBUCK];
    __shared__ int bcur[NBUCK];
    __shared__ int s[256];
    __shared__ int staged_val[BINA_EDGES];
    __shared__ int staged_addr[BINA_EDGES];
    const int tid = threadIdx.x;
    const int base = blockIdx.x * BINA_EDGES;
    const int ecount = min(BINA_EDGES, N_EDGES - base);

    if (tid < NBUCK) bcur[tid] = 0;
    __syncthreads();
    for (int j = tid; j < ecount; j += 256) {
        int d = dst[base + j];
        atomicAdd(&bcur[d >> BSHIFT], 1);
    }
    __syncthreads();
    int own = (tid < NBUCK) ? bcur[tid] : 0;
    s[tid] = own;
    __syncthreads();
    for (int off = 1; off < 256; off <<= 1) {
        int u = (tid >= off) ? s[tid - off] : 0;
        __syncthreads();
        s[tid] += u;
        __syncthreads();
    }
    if (tid < NBUCK) {
        int excl = s[tid] - own;
        bstart[tid] = excl;
        int resv = atomicAdd(&gcursor[tid], own);
        addrbase[tid] = resv - excl;
    }
    __syncthreads();
    if (tid < NBUCK) bcur[tid] = bstart[tid];
    __syncthreads();
    for (int j = tid; j < ecount; j += 256) {
        int d = dst[base + j];
        int sr = src[base + j];
        int bk = d >> BSHIFT;
        int lpos = atomicAdd(&bcur[bk], 1);
        staged_val[lpos] = ((d & ((1 << BSHIFT) - 1)) << 17) | sr;
        staged_addr[lpos] = addrbase[bk] + lpos;
    }
    __syncthreads();
    for (int j = tid; j < ecount; j += 256)
        tmp[staged_addr[j]] = staged_val[j];
}

// Pass B: one block per bucket; per-block redundant scan of gcursor replaces a
// separate bucket_scan launch (saves a <<<1,128>>> serialization point).
__global__ __launch_bounds__(256) void binB_kernel(
    const int* __restrict__ tmp, const int* __restrict__ gcursor,
    int* __restrict__ row_ptr, int* __restrict__ srcs) {
    __shared__ int hist[1024];
    __shared__ int tsum[256];
    __shared__ int sscan[128];
    const int b = blockIdx.x;
    const int tid = threadIdx.x;
    const int base = b * SLAB;
    const int cnt = gcursor[b] - base;
    const int node0 = b << BSHIFT;
    const int nodes_in = min(1024, N_NODES - node0);

    if (b == 0 && tid == 0) row_ptr[N_NODES] = N_EDGES;

    if (tid < 128) {
        int vv = (tid < NBUCK) ? (gcursor[tid] - tid * SLAB) : 0;
        sscan[tid] = vv;
    }
    __syncthreads();
    for (int off = 1; off < 128; off <<= 1) {
        int u = 0;
        if (tid < 128 && tid >= off) u = sscan[tid - off];
        __syncthreads();
        if (tid < 128) sscan[tid] += u;
        __syncthreads();
    }
    const int gb = sscan[b] - cnt;

    for (int i = tid; i < 1024; i += 256) hist[i] = 0;
    __syncthreads();
    for (int i = tid; i < cnt; i += 256)
        atomicAdd(&hist[tmp[base + i] >> 17], 1);
    __syncthreads();
    int v[4], local = 0;
#pragma unroll
    for (int j = 0; j < 4; ++j) {
        v[j] = hist[tid * 4 + j];
        local += v[j];
    }
    tsum[tid] = local;
    __syncthreads();
    for (int off = 1; off < 256; off <<= 1) {
        int u = (tid >= off) ? tsum[tid - off] : 0;
        __syncthreads();
        tsum[tid] += u;
        __syncthreads();
    }
    int run = tsum[tid] - local;
#pragma unroll
    for (int j = 0; j < 4; ++j) {
        hist[tid * 4 + j] = run;
        run += v[j];
    }
    __syncthreads();
    for (int i = tid; i < nodes_in; i += 256)
        row_ptr[node0 + i] = gb + hist[i];
    __syncthreads();
    for (int i = tid; i < cnt; i += 256) {
        int e = tmp[base + i];
        int pos = atomicAdd(&hist[e >> 17], 1);
        srcs[gb + pos] = e & 0x1FFFF;
    }
}

// ---------------- prep: weight convert + gcursor init (h0 now fused in mm3f) --
__device__ inline void conv_one(int idx, int K, const float* __restrict__ Wl,
                                const float* __restrict__ Wr, const float* __restrict__ Ws,
                                unsigned short* __restrict__ wt) {
    int n = idx / K;
    int k = idx - n * K;
    int sec = n >> 7;
    int nn = n & 127;
    const float* W = (sec == 0) ? Wl : (sec == 1) ? Wr : Ws;
    wt[idx] = bf16_rn(W[k * 128 + nn]);
}

__global__ void prep_kernel(
    const float* __restrict__ fWl, const float* __restrict__ fWr, const float* __restrict__ fWs,
    const float* __restrict__ mWl, const float* __restrict__ mWr, const float* __restrict__ mWs,
    const float* __restrict__ lWl, const float* __restrict__ lWr, const float* __restrict__ lWs,
    unsigned short* __restrict__ wt_f, unsigned short* __restrict__ wt_m,
    unsigned short* __restrict__ wt_l, int* __restrict__ gcursor) {
    int t = blockIdx.x * 256 + threadIdx.x;
    if (t < NBUCK) gcursor[t] = t * SLAB;
    if (t < 384 * 32) {
        conv_one(t, 32, fWl, fWr, fWs, wt_f);
    } else if (t < 384 * 32 + 384 * 128) {
        conv_one(t - 384 * 32, 128, mWl, mWr, mWs, wt_m);
    } else if (t < CONV_TOTAL) {
        conv_one(t - 384 * 32 - 384 * 128, 128, lWl, lWr, lWs, wt_l);
    }
}

// ---------------- mm3f: FUSED h0 + layer-f projection -----------------------
// Per 64-row 1-wave block: (1) h0 = relu(x@W0) via 16 MFMAs, C-fragments
// written to a private 80-B-stride LDS tile (block-local fusion: deletes the
// h0 global write+read, 12.8 MB, and one launch); (2) read row a-fragments
// back (single wave -> no barrier; compiler orders same-array ds ops) and run
// the r5-proven K=32 section loop with LDS-staged dense output stores.
__global__ __launch_bounds__(64) void mm3f_kernel(
    const float* __restrict__ x, const float* __restrict__ W0,
    const unsigned short* __restrict__ Wt,
    const float* __restrict__ bl, const float* __restrict__ br, const float* __restrict__ bs,
    const float* __restrict__ cb,
    unsigned short* __restrict__ xl_bf, unsigned short* __restrict__ xr_bf,
    unsigned short* __restrict__ sk_bf) {
    __shared__ uint4 tile4[64 * 10];          // 10240 B output staging
    __shared__ unsigned short hT[64 * 40];    // 64 rows x 80 B = 5120 B h-tile
    const int lane = threadIdx.x & 63;
    const int q = lane >> 4;
    const int li = lane & 15;
    const int r0 = blockIdx.x * 64;

    // ---- h0 = relu(x @ W0) for rows [r0, r0+64) ----
    v8s xa[4][2];
#pragma unroll
    for (int mi = 0; mi < 4; ++mi) {
        int row = r0 + mi * 16 + li;
        row = row < N_NODES ? row : N_NODES - 1;
#pragma unroll
        for (int ks = 0; ks < 2; ++ks) {
            const float* xp = &x[(size_t)row * 64 + ks * 32 + q * 8];
            v8s v;
#pragma unroll
            for (int j = 0; j < 8; ++j) v[j] = (short)bf16_rn(xp[j]);
            xa[mi][ks] = v;
        }
    }
    v8s w0f[2][2];
#pragma unroll
    for (int ks = 0; ks < 2; ++ks)
#pragma unroll
        for (int n2 = 0; n2 < 2; ++n2) {
            v8s v;
#pragma unroll
            for (int j = 0; j < 8; ++j)
                v[j] = (short)bf16_rn(W0[(ks * 32 + q * 8 + j) * 32 + n2 * 16 + li]);
            w0f[ks][n2] = v;
        }
    v4f hacc[4][2];
#pragma unroll
    for (int mi = 0; mi < 4; ++mi)
#pragma unroll
        for (int n2 = 0; n2 < 2; ++n2) hacc[mi][n2] = (v4f)(0.f);
#pragma unroll
    for (int ks = 0; ks < 2; ++ks)
#pragma unroll
        for (int mi = 0; mi < 4; ++mi)
#pragma unroll
            for (int n2 = 0; n2 < 2; ++n2)
                hacc[mi][n2] = __builtin_amdgcn_mfma_f32_16x16x32_bf16(w0f[ks][n2], xa[mi][ks], hacc[mi][n2], 0, 0, 0);
    // relu + pack -> LDS h-tile (same C-fragment staging layout as the epilogue)
#pragma unroll
    for (int n2 = 0; n2 < 2; ++n2)
#pragma unroll
        for (int mi = 0; mi < 4; ++mi) {
            v4f v = hacc[mi][n2];
            uint2 pk;
            pk.x = pack_bf16(fmaxf(v[0], 0.f), fmaxf(v[1], 0.f));
            pk.y = pack_bf16(fmaxf(v[2], 0.f), fmaxf(v[3], 0.f));
            *(uint2*)((char*)hT + (mi * 16 + li) * 80 + n2 * 32 + q * 8) = pk;
        }
    // read back row a-fragments (K=32: one v8s per row at byte q*16)
    v8s a[4];
#pragma unroll
    for (int mi = 0; mi < 4; ++mi)
        a[mi] = *(const v8s*)((const char*)hT + (mi * 16 + li) * 80 + q * 16);

    // ---- K=32 section loop (identical to proven mm3<32>) ----
    const int frow = lane >> 3;
    const int fchunk = lane & 7;

    for (int t = 0; t < 6; ++t) {
        const int sec = t >> 1;
        const int c0 = (t & 1) * 64;
        v4f acc[4][4];
#pragma unroll
        for (int mi = 0; mi < 4; ++mi)
#pragma unroll
            for (int ni = 0; ni < 4; ++ni) acc[mi][ni] = (v4f)(0.f);

        v8s b[4];
#pragma unroll
        for (int ni = 0; ni < 4; ++ni) {
            int col = sec * 128 + c0 + ni * 16 + li;
            b[ni] = *(const v8s*)&Wt[(size_t)col * 32 + q * 8];
        }
#pragma unroll
        for (int mi = 0; mi < 4; ++mi)
#pragma unroll
            for (int ni = 0; ni < 4; ++ni)
                acc[mi][ni] = __builtin_amdgcn_mfma_f32_16x16x32_bf16(b[ni], a[mi], acc[mi][ni], 0, 0, 0);

        unsigned short* dstp = (sec == 0) ? xl_bf : (sec == 1) ? xr_bf : sk_bf;
#pragma unroll
        for (int ni = 0; ni < 4; ++ni) {
            int cbase = c0 + ni * 16 + q * 4;
            float4 b4;
            if (sec == 0) b4 = *(const float4*)&bl[cbase];
            else if (sec == 1) b4 = *(const float4*)&br[cbase];
            else {
                float4 t1 = *(const float4*)&bs[cbase];
                float4 t2 = *(const float4*)&cb[cbase];
                b4 = make_float4(t1.x + t2.x, t1.y + t2.y, t1.z + t2.z, t1.w + t2.w);
            }
#pragma unroll
            for (int mi = 0; mi < 4; ++mi) {
                v4f v = acc[mi][ni];
                uint2 pk;
                pk.x = pack_bf16(v[0] + b4.x, v[1] + b4.y);
                pk.y = pack_bf16(v[2] + b4.z, v[3] + b4.w);
                int lrow = mi * 16 + li;
                *(uint2*)((char*)tile4 + lrow * 160 + ni * 32 + q * 8) = pk;
            }
        }
#pragma unroll
        for (int j = 0; j < 8; ++j) {
            int lrow = j * 8 + frow;
            int grow = r0 + lrow;
            if (grow < N_NODES) {
                uint4 v = *(const uint4*)((const char*)tile4 + lrow * 160 + fchunk * 16);
                *(uint4*)((char*)dstp + (size_t)grow * 256 + c0 * 2 + fchunk * 16) = v;
            }
        }
    }
}

// ---------------- MFMA mm3: [N,128]bf16 @ Wt^T -> xl|xr|skip all bf16 --------
// r5-proven shape: 64 rows per 1-wave block (r4's 32-row and r6's 4-wave
// variants both regressed). C-fragments staged in LDS (160-B row stride),
// flushed with full-wave dense uint4 stores: every 128-B line written once.
template <int K>
__global__ __launch_bounds__(64) void mm3_mfma(
    const unsigned short* __restrict__ A, const unsigned short* __restrict__ Wt,
    const float* __restrict__ bl, const float* __restrict__ br, const float* __restrict__ bs,
    const float* __restrict__ cb,
    unsigned short* __restrict__ xl_bf, unsigned short* __restrict__ xr_bf,
    unsigned short* __restrict__ sk_bf) {
    __shared__ uint4 tile4[64 * 10];  // 64 rows x 160 B
    const int lane = threadIdx.x & 63;
    const int q = lane >> 4;
    const int li = lane & 15;
    const int r0 = blockIdx.x * 64;
    constexpr int KS = K / 32;

    v8s a[4][KS];
#pragma unroll
    for (int mi = 0; mi < 4; ++mi) {
        int row = r0 + mi * 16 + li;
        row = row < N_NODES ? row : N_NODES - 1;
#pragma unroll
        for (int ks = 0; ks < KS; ++ks)
            a[mi][ks] = *(const v8s*)&A[(size_t)row * K + ks * 32 + q * 8];
    }

    const int frow = lane >> 3;
    const int fchunk = lane & 7;

    for (int t = 0; t < 6; ++t) {
        const int sec = t >> 1;
        const int c0 = (t & 1) * 64;
        v4f acc[4][4];
#pragma unroll
        for (int mi = 0; mi < 4; ++mi)
#pragma unroll
            for (int ni = 0; ni < 4; ++ni) acc[mi][ni] = (v4f)(0.f);

#pragma unroll
        for (int ks = 0; ks < KS; ++ks) {
            v8s b[4];
#pragma unroll
            for (int ni = 0; ni < 4; ++ni) {
                int col = sec * 128 + c0 + ni * 16 + li;
                b[ni] = *(const v8s*)&Wt[(size_t)col * K + ks * 32 + q * 8];
            }
#pragma unroll
            for (int mi = 0; mi < 4; ++mi)
#pragma unroll
                for (int ni = 0; ni < 4; ++ni)
                    acc[mi][ni] = __builtin_amdgcn_mfma_f32_16x16x32_bf16(b[ni], a[mi][ks], acc[mi][ni], 0, 0, 0);
        }

        unsigned short* dstp = (sec == 0) ? xl_bf : (sec == 1) ? xr_bf : sk_bf;
#pragma unroll
        for (int ni = 0; ni < 4; ++ni) {
            int cbase = c0 + ni * 16 + q * 4;
            float4 b4;
            if (sec == 0) b4 = *(const float4*)&bl[cbase];
            else if (sec == 1) b4 = *(const float4*)&br[cbase];
            else {
                float4 t1 = *(const float4*)&bs[cbase];
                float4 t2 = *(const float4*)&cb[cbase];
                b4 = make_float4(t1.x + t2.x, t1.y + t2.y, t1.z + t2.z, t1.w + t2.w);
            }
#pragma unroll
            for (int mi = 0; mi < 4; ++mi) {
                v4f v = acc[mi][ni];
                uint2 pk;
                pk.x = pack_bf16(v[0] + b4.x, v[1] + b4.y);
                pk.y = pack_bf16(v[2] + b4.z, v[3] + b4.w);
                int lrow = mi * 16 + li;
                *(uint2*)((char*)tile4 + lrow * 160 + ni * 32 + q * 8) = pk;
            }
        }
#pragma unroll
        for (int j = 0; j < 8; ++j) {
            int lrow = j * 8 + frow;
            int grow = r0 + lrow;
            if (grow < N_NODES) {
                uint4 v = *(const uint4*)((const char*)tile4 + lrow * 160 + fchunk * 16);
                *(uint4*)((char*)dstp + (size_t)grow * 256 + c0 * 2 + fchunk * 16) = v;
            }
        }
    }
}

// ---------------- GATv2 aggregation ----------------
// One wave per node (natural dispatch order = sliding contiguous node window;
// r2's strided persistent variant proved reordering costs ~80MB of fetch).
// Depth-3 rotating prefetch on the xl[src] gathers. Duration is traffic-bound
// at ~3.2 TB/s of L2-miss (FETCH+WRITE) = ~196MB -> ~60us floor, reached.
// Fused kernels (r6 4-wave, r8 aggmm) both regressed: the gather phase needs
// maximal wave residency, incompatible with big-LDS/VGPR fusion footprints.
#define GATHER4(S) (*(const uint4*)((const char*)xlb4 + (((unsigned)(S)) << 8) + ((unsigned)li << 4)))

#define AGG_BODY(XC, SVC, CB)                                               \
    {                                                                       \
        float xf[8];                                                        \
        unpack8(XC, xf);                                                    \
        bool vld = (CB) + g < end;                                          \
        if ((CB) + 12 < end) XC = GATHER4(SVC);                             \
        if ((CB) + 24 < end) {                                              \
            int ii = (CB) + 24 + g;                                         \
            SVC = srcs[ii < end ? ii : em1];                                \
        }                                                                   \
        float p1 = 0.f, p2 = 0.f;                                           \
        _Pragma("unroll") for (int i = 0; i < 8; ++i) {                     \
            float e_ = xf[i] + xr_f[i];                                     \
            p1 = fmaf(e_, at_f[i], p1);                                     \
            p2 = fmaf(fabsf(e_), at_f[i], p2);                              \
        }                                                                   \
        float p = fmaf(0.6f, p1, 0.4f * p2);                                \
        p += __shfl_xor(p, 1);                                              \
        p += __shfl_xor(p, 2);                                              \
        float w = vld ? __expf(p) : 0.f;                                    \
        lsum += w;                                                          \
        _Pragma("unroll") for (int i = 0; i < 8; ++i)                       \
            acc[i] = fmaf(xf[i], w, acc[i]);                                \
    }

__global__ __launch_bounds__(256, 7) void agg_kernel(
    const uint4* __restrict__ xlb4, const uint4* __restrict__ xrb4,
    const uint4* __restrict__ skb4, const int* __restrict__ row_ptr,
    const int* __restrict__ srcs, const float* __restrict__ att,
    unsigned* __restrict__ out_bf, float* __restrict__ out_f,
    int write_bf, int do_relu, int do_norm) {
    int n = (blockIdx.x * blockDim.x + threadIdx.x) >> 6;
    if (n >= N_NODES) return;
    int lane = threadIdx.x & 63;
    int g = lane >> 4, li = lane & 15;

    // n is wave-uniform -> scalarize loop bounds so all pipeline control is SALU
    const int beg = __builtin_amdgcn_readfirstlane(row_ptr[n]);
    const int end = __builtin_amdgcn_readfirstlane(row_ptr[n + 1]);

    // issue per-node loads early; sk only needed in epilogue but is in flight
    uint4 xru = xrb4[(size_t)n * 16 + li];
    uint4 sku = skb4[(size_t)n * 16 + li];

    float at_f[8];
    *(float4*)&at_f[0] = *(const float4*)&att[li * 8];
    *(float4*)&at_f[4] = *(const float4*)&att[li * 8 + 4];
    float xr_f[8];
    unpack8(xru, xr_f);

    float acc[8];
#pragma unroll
    for (int i = 0; i < 8; ++i) acc[i] = 0.f;
    float lsum = 0.f;

    if (beg < end) {
        const int em1 = end - 1;
#define SRC_AT(Q) ({ int _ii = beg + (Q) * 4 + g; srcs[_ii < end ? _ii : em1]; })
        int sv0 = SRC_AT(0), sv1 = SRC_AT(1), sv2 = SRC_AT(2);
        uint4 x0 = GATHER4(sv0);
        uint4 x1 = GATHER4(sv1);
        uint4 x2 = GATHER4(sv2);
        sv0 = SRC_AT(3);
        sv1 = SRC_AT(4);
        sv2 = SRC_AT(5);
#undef SRC_AT

        for (int cb = beg; cb < end; cb += 12) {
            AGG_BODY(x0, sv0, cb)
            if (cb + 4 < end) AGG_BODY(x1, sv1, cb + 4)
            if (cb + 8 < end) AGG_BODY(x2, sv2, cb + 8)
        }
    }

#pragma unroll
    for (int i = 0; i < 8; ++i) {
        acc[i] += __shfl_xor(acc[i], 16);
        acc[i] += __shfl_xor(acc[i], 32);
    }
    lsum += __shfl_xor(lsum, 16);
    lsum += __shfl_xor(lsum, 32);

    float inv = (lsum > 0.f) ? 1.f / lsum : 0.f;
    float sk_f[8];
    unpack8(sku, sk_f);
    float o[8];
#pragma unroll
    for (int i = 0; i < 8; ++i) o[i] = fmaf(acc[i], inv, sk_f[i]);
    if (do_relu) {
#pragma unroll
        for (int i = 0; i < 8; ++i) o[i] = fmaxf(o[i], 0.f);
    }
    if (do_norm) {
        float ss = 0.f;
#pragma unroll
        for (int i = 0; i < 8; ++i) ss = fmaf(o[i], o[i], ss);
        ss += __shfl_xor(ss, 1);
        ss += __shfl_xor(ss, 2);
        ss += __shfl_xor(ss, 4);
        ss += __shfl_xor(ss, 8);
        float r = 1.0f / sqrtf(ss);
#pragma unroll
        for (int i = 0; i < 8; ++i) o[i] *= r;
    }

    // full-wave dense stores: every lane writes its g-quarter of the li-pair
    // (post-xor-reduction ALL lanes hold the node's full per-head values)
    float oa = (g == 0) ? o[0] : (g == 1) ? o[2] : (g == 2) ? o[4] : o[6];
    float ob = (g == 0) ? o[1] : (g == 1) ? o[3] : (g == 2) ? o[5] : o[7];
    if (write_bf) {
        *(unsigned*)((char*)out_bf + (size_t)n * 256 + li * 16 + g * 4) = pack_bf16(oa, ob);
    } else {
        float2 v2 = make_float2(oa, ob);
        *(float2*)((char*)out_f + (size_t)n * 512 + li * 32 + g * 8) = v2;
    }
}

// ---------------- launch ----------------
extern "C" void kernel_launch(void* const* d_in, const int* in_sizes, int n_in,
                              void* d_out, int out_size, void* d_ws, size_t ws_size,
                              hipStream_t stream) {
    const float* x = (const float*)d_in[0];
    const int* ei = (const int*)d_in[1];
    const int* src = ei;
    const int* dst = ei + N_EDGES;
    const float* W0 = (const float*)d_in[2];

    const float* f_p[8];
    const float* m_p[8];
    const float* l_p[8];
    for (int i = 0; i < 8; ++i) f_p[i] = (const float*)d_in[3 + i];
    for (int i = 0; i < 8; ++i) m_p[i] = (const float*)d_in[11 + i];
    for (int i = 0; i < 8; ++i) l_p[i] = (const float*)d_in[19 + i];
    // indices: 0=Wl 1=bl 2=Wr 3=br 4=att 5=cb 6=Ws 7=bs

    char* ws = (char*)d_ws;
    unsigned short* xl_bf = (unsigned short*)ws; ws += (size_t)N_NODES * 128 * 2;  // 25.6 MB
    unsigned short* xr_bf = (unsigned short*)ws; ws += (size_t)N_NODES * 128 * 2;
    unsigned short* sk_bf = (unsigned short*)ws; ws += (size_t)N_NODES * 128 * 2;
    unsigned short* h_bf = (unsigned short*)ws;  ws += (size_t)N_NODES * 128 * 2;
    int* row_ptr = (int*)ws;       ws += (size_t)(N_NODES + 1) * 4;
    int* srcs = (int*)ws;          ws += (size_t)N_EDGES * 4;
    int* tmp = (int*)ws;           ws += (size_t)NBUCK * SLAB * 4;   // 4.8 MB slabs
    int* gcursor = (int*)ws;       ws += (size_t)NBUCK * 4;
    unsigned short* wt_f = (unsigned short*)ws; ws += (size_t)384 * 32 * 2;
    unsigned short* wt_m = (unsigned short*)ws; ws += (size_t)384 * 128 * 2;
    unsigned short* wt_l = (unsigned short*)ws; ws += (size_t)384 * 128 * 2;

    // prep (weight convert + gcursor init), then CSR build (scan fused into binB)
    prep_kernel<<<CONV_BLOCKS, 256, 0, stream>>>(
        f_p[0], f_p[2], f_p[6], m_p[0], m_p[2], m_p[6], l_p[0], l_p[2], l_p[6],
        wt_f, wt_m, wt_l, gcursor);
    binA_kernel<<<(N_EDGES + BINA_EDGES - 1) / BINA_EDGES, 256, 0, stream>>>(src, dst, gcursor, tmp);
    binB_kernel<<<NBUCK, 256, 0, stream>>>(tmp, gcursor, row_ptr, srcs);

    const int gmm = (N_NODES + 63) / 64;
    const int gagg = (N_NODES * 64) / 256;
    float* out = (float*)d_out;

    // layer f: fused h0 + projection (din=32) straight from x
    mm3f_kernel<<<gmm, 64, 0, stream>>>(x, W0, wt_f, f_p[1], f_p[3], f_p[7], f_p[5],
                                        xl_bf, xr_bf, sk_bf);
    agg_kernel<<<gagg, 256, 0, stream>>>((uint4*)xl_bf, (uint4*)xr_bf, (uint4*)sk_bf,
                                         row_ptr, srcs, f_p[4],
                                         (unsigned*)h_bf, nullptr, 1, 1, 0);

    // 3x layer m (din=128, shared weights), relu
    for (int it = 0; it < 3; ++it) {
        mm3_mfma<128><<<gmm, 64, 0, stream>>>(h_bf, wt_m, m_p[1], m_p[3], m_p[7], m_p[5],
                                              xl_bf, xr_bf, sk_bf);
        agg_kernel<<<gagg, 256, 0, stream>>>((uint4*)xl_bf, (uint4*)xr_bf, (uint4*)sk_bf,
                                             row_ptr, srcs, m_p[4],
                                             (unsigned*)h_bf, nullptr, 1, 1, 0);
    }

    // layer l (din=128), no relu, L2 normalize, write fp32 to d_out
    mm3_mfma<128><<<gmm, 64, 0, stream>>>(h_bf, wt_l, l_p[1], l_p[3], l_p[7], l_p[5],
                                          xl_bf, xr_bf, sk_bf);
    agg_kernel<<<gagg, 256, 0, stream>>>((uint4*)xl_bf, (uint4*)xr_bf, (uint4*)sk_bf,
                                         row_ptr, srcs, l_p[4],
                                         nullptr, out, 0, 0, 1);
}